// Round 7
// baseline (172.958 us; speedup 1.0000x reference)
//
#include <hip/hip_runtime.h>
#include <hip/hip_bf16.h>

#define D 128
#define BSH 7            // 128 dsts per bin
#define BDST 128
#define NCH 256          // edge chunks
#define CAP 6144         // local CSR capacity per bin (mean 4096, +32 sigma)

typedef __attribute__((ext_vector_type(8))) short short8;
typedef __attribute__((ext_vector_type(4))) float f32x4;

__device__ __forceinline__ unsigned short f2bf(float f) {
  unsigned u = __float_as_uint(f);
  unsigned r = (u + 0x7FFFu + ((u >> 16) & 1u)) >> 16;
  return (unsigned short)r;
}

// ---------------- K0: W fp32 -> bf16 ------------------------------------------
__global__ __launch_bounds__(256) void k_wconv(const float* __restrict__ W,
                                               unsigned short* __restrict__ Wb) {
  const int i = blockIdx.x * 256 + threadIdx.x;
  float4 f = ((const float4*)W)[i];
  ushort4 o;
  o.x = f2bf(f.x); o.y = f2bf(f.y); o.z = f2bf(f.z); o.w = f2bf(f.w);
  ((ushort4*)Wb)[i] = o;
}

// ---------------- K1: z = h@W^T (MFMA) + fused s_fc AND emb dots --------------
// Wave = 16 nodes. Outputs: paired-dword bf16 z, final a_src/a_dst.
__global__ __launch_bounds__(256) void k_lin(const float* __restrict__ h,
                                             const unsigned short* __restrict__ Wb,
                                             const float* __restrict__ w_fc,
                                             const float* __restrict__ emb,
                                             const float* __restrict__ w_emb,
                                             unsigned* __restrict__ zd,
                                             float* __restrict__ a_src,
                                             float* __restrict__ a_dst, int n) {
  __shared__ float sfs[4][16], sfd[4][16];
  const int lane = threadIdx.x & 63;
  const int wid = threadIdx.x >> 6;
  const int m0 = blockIdx.x * 64 + wid * 16;
  if (m0 >= n) return;
  const int c = lane & 15;
  const int g = lane >> 4;

  int arow = m0 + c;
  if (arow >= n) arow = n - 1;
  const float4* hrow = (const float4*)(h + (size_t)arow * 128);

  short8 afr[4];
#pragma unroll
  for (int s = 0; s < 4; ++s) {
    float4 f0 = hrow[8 * s + 2 * g];
    float4 f1 = hrow[8 * s + 2 * g + 1];
    short8 a;
    a[0] = (short)f2bf(f0.x); a[1] = (short)f2bf(f0.y);
    a[2] = (short)f2bf(f0.z); a[3] = (short)f2bf(f0.w);
    a[4] = (short)f2bf(f1.x); a[5] = (short)f2bf(f1.y);
    a[6] = (short)f2bf(f1.z); a[7] = (short)f2bf(f1.w);
    afr[s] = a;
  }

  f32x4 acc[8];
#pragma unroll
  for (int t = 0; t < 8; ++t) acc[t] = (f32x4){0.f, 0.f, 0.f, 0.f};

#pragma unroll
  for (int s = 0; s < 4; ++s) {
#pragma unroll
    for (int t = 0; t < 8; ++t) {
      short8 b = *(const short8*)(Wb + ((size_t)(t * 16 + c) * 128 + 32 * s + 8 * g));
      acc[t] = __builtin_amdgcn_mfma_f32_16x16x32_bf16(afr[s], b, acc[t], 0, 0, 0);
    }
  }

  float wfs[8], wfd[8];
#pragma unroll
  for (int t = 0; t < 8; ++t) {
    wfs[t] = w_fc[t * 16 + c];
    wfd[t] = w_fc[128 + t * 16 + c];
  }

  const int rbase = m0 + 4 * g;
#pragma unroll
  for (int r = 0; r < 4; ++r) {
    const int row = rbase + r;
    if (row < n) {
#pragma unroll
      for (int tp = 0; tp < 4; ++tp) {
        unsigned dw = ((unsigned)f2bf(acc[tp + 4][r]) << 16) | (unsigned)f2bf(acc[tp][r]);
        zd[(size_t)row * 64 + tp * 16 + c] = dw;
      }
    }
    float ps = 0.f, pd = 0.f;
#pragma unroll
    for (int t = 0; t < 8; ++t) {
      ps += acc[t][r] * wfs[t];
      pd += acc[t][r] * wfd[t];
    }
#pragma unroll
    for (int off = 1; off < 16; off <<= 1) {
      ps += __shfl_xor(ps, off, 64);
      pd += __shfl_xor(pd, off, 64);
    }
    if (c == 0) {
      sfs[wid][4 * g + r] = ps;
      sfd[wid][4 * g + r] = pd;
    }
  }
  __syncthreads();

  // fused embedding dots: lane = 4*node_local + quarter; 8KB contiguous/wave
  const int nloc = lane >> 2;
  const int qc = lane & 3;
  const int node2 = m0 + nloc;
  float es = 0.f, ed = 0.f;
  if (node2 < n) {
    const float4* er = (const float4*)(emb + (size_t)node2 * 128 + qc * 32);
    const float4* wsp = (const float4*)(w_emb + qc * 32);
    const float4* wdp = (const float4*)(w_emb + 128 + qc * 32);
#pragma unroll
    for (int j = 0; j < 8; ++j) {
      float4 e4 = er[j], s4 = wsp[j], d4 = wdp[j];
      es += e4.x * s4.x + e4.y * s4.y + e4.z * s4.z + e4.w * s4.w;
      ed += e4.x * d4.x + e4.y * d4.y + e4.z * d4.z + e4.w * d4.w;
    }
  }
  es += __shfl_xor(es, 1, 64); es += __shfl_xor(es, 2, 64);
  ed += __shfl_xor(ed, 1, 64); ed += __shfl_xor(ed, 2, 64);
  if (qc == 0 && node2 < n) {
    a_src[node2] = es + sfs[wid][nloc];
    a_dst[node2] = ed + sfd[wid][nloc];
  }
}

// ---------------- CSR build pass 1: per-chunk bin histogram -------------------
__global__ __launch_bounds__(256) void k_chist(const int* __restrict__ dst,
                                               int* __restrict__ cnt,
                                               int E, int NB, int CHSZ) {
  __shared__ int hl[512];
  const int tid = threadIdx.x, c = blockIdx.x;
  for (int i = tid; i < NB; i += 256) hl[i] = 0;
  __syncthreads();
  const int beg = c * CHSZ, end = min(beg + CHSZ, E);
  for (int i = beg + tid; i < end; i += 256) atomicAdd(&hl[dst[i] >> BSH], 1);
  __syncthreads();
  for (int b = tid; b < NB; b += 256) cnt[(size_t)b * NCH + c] = hl[b];
}

// ---------------- scan: ks1 (tile sums), ks2 (scan partials), ks3 (apply) -----
__global__ __launch_bounds__(256) void ks1(const int* __restrict__ cnt,
                                           int* __restrict__ partial, int M) {
  const int tid = threadIdx.x;
  const int t0 = blockIdx.x * 1024 + tid * 4;
  int s = 0;
  if (t0 + 3 < M) {
    int4 v = *(const int4*)(cnt + t0);
    s = v.x + v.y + v.z + v.w;
  } else {
    for (int j = 0; j < 4; ++j)
      if (t0 + j < M) s += cnt[t0 + j];
  }
#pragma unroll
  for (int off = 32; off; off >>= 1) s += __shfl_xor(s, off, 64);
  __shared__ int w[4];
  if ((tid & 63) == 0) w[tid >> 6] = s;
  __syncthreads();
  if (tid == 0) partial[blockIdx.x] = w[0] + w[1] + w[2] + w[3];
}

__global__ __launch_bounds__(256) void ks2(const int* __restrict__ partial,
                                           int* __restrict__ chunk_off, int P) {
  __shared__ int s[256];
  const int tid = threadIdx.x;
  int v = (tid < P) ? partial[tid] : 0;
  s[tid] = v;
  __syncthreads();
  for (int off = 1; off < 256; off <<= 1) {
    int a = (tid >= off) ? s[tid - off] : 0;
    __syncthreads();
    s[tid] += a;
    __syncthreads();
  }
  if (tid < P) chunk_off[tid] = s[tid] - v;
}

__global__ __launch_bounds__(256) void ks3(int* __restrict__ cnt,
                                           const int* __restrict__ chunk_off, int M) {
  const int tid = threadIdx.x;
  const int t0 = blockIdx.x * 1024 + tid * 4;
  int v[4];
  int s = 0;
#pragma unroll
  for (int j = 0; j < 4; ++j) {
    v[j] = (t0 + j < M) ? cnt[t0 + j] : 0;
    s += v[j];
  }
  __shared__ int sh[256];
  sh[tid] = s;
  __syncthreads();
  for (int off = 1; off < 256; off <<= 1) {
    int a = (tid >= off) ? sh[tid - off] : 0;
    __syncthreads();
    sh[tid] += a;
    __syncthreads();
  }
  int excl = chunk_off[blockIdx.x] + sh[tid] - s;
#pragma unroll
  for (int j = 0; j < 4; ++j) {
    if (t0 + j < M) cnt[t0 + j] = excl;
    excl += v[j];
  }
}

// ---------------- CSR build pass 2: chunk scatter to bin regions --------------
__global__ __launch_bounds__(256) void k_cscat(const int* __restrict__ src,
                                               const int* __restrict__ dst,
                                               const int* __restrict__ S,
                                               unsigned* __restrict__ binrec,
                                               int E, int NB, int CHSZ) {
  __shared__ int cur[512];
  const int tid = threadIdx.x, c = blockIdx.x;
  for (int b = tid; b < NB; b += 256) cur[b] = S[(size_t)b * NCH + c];
  __syncthreads();
  const int beg = c * CHSZ, end = min(beg + CHSZ, E);
  for (int i = beg + tid; i < end; i += 256) {
    int d = dst[i];
    int pos = atomicAdd(&cur[d >> BSH], 1);
    binrec[pos] = ((unsigned)src[i] << BSH) | (unsigned)(d & (BDST - 1));
  }
}

// ---------------- K6: fused per-bin CSR build (LDS) + aggregation -------------
// Block = bin (128 dsts). Pass A: hist over binrec range. Scan. Pass B: scatter
// src ids into LDS-local CSR. Then wave w aggregates dsts w*32..w*32+31 with the
// proven 4x16-group gather loop (zd paired-dword bf16 rows).
__global__ __launch_bounds__(256) void k_bagg(const unsigned* __restrict__ binrec,
                                              const int* __restrict__ S,
                                              const unsigned* __restrict__ zd,
                                              const float* __restrict__ a_src,
                                              const float* __restrict__ a_dst,
                                              float* __restrict__ out,
                                              int n, int E, int NB) {
  __shared__ int csrl[CAP];
  __shared__ int hist[BDST];
  __shared__ int lrow[BDST];   // inclusive scan (end offsets)
  __shared__ int cur[BDST];
  const int tid = threadIdx.x, b = blockIdx.x;
  const int base = S[(size_t)b * NCH];
  const int next = (b + 1 < NB) ? S[(size_t)(b + 1) * NCH] : E;
  const int cntb = next - base;

  if (tid < BDST) hist[tid] = 0;
  __syncthreads();
  for (int i = tid; i < cntb; i += 256)
    atomicAdd(&hist[binrec[base + i] & (BDST - 1)], 1);
  __syncthreads();
  if (tid < BDST) lrow[tid] = hist[tid];
  __syncthreads();
  for (int off = 1; off < BDST; off <<= 1) {
    int a = (tid < BDST && tid >= off) ? lrow[tid - off] : 0;
    __syncthreads();
    if (tid < BDST) lrow[tid] += a;
    __syncthreads();
  }
  if (tid < BDST) cur[tid] = lrow[tid] - hist[tid];
  __syncthreads();
  for (int i = tid; i < cntb; i += 256) {
    unsigned r = binrec[base + i];
    int pos = atomicAdd(&cur[r & (BDST - 1)], 1);
    csrl[pos] = (int)(r >> BSH);
  }
  __syncthreads();

  const int lane = tid & 63;
  const int wid = tid >> 6;
  const int grp = lane >> 4;
  const int sub = lane & 15;

  for (int k = 0; k < 32; ++k) {
    const int dl = wid * 32 + k;
    const int v = b * BDST + dl;
    if (v >= n) break;
    const int end = lrow[dl];
    const int beg = end - hist[dl];
    const float adv = a_dst[v];

    float accf[8];
#pragma unroll
    for (int j = 0; j < 8; ++j) accf[j] = 0.f;
    float ews = 0.f;

#pragma unroll 2
    for (int i = beg + grp; i < end; i += 4) {
      const int u = csrl[i];
      const float a = a_src[u] + adv;
      const float e = a > 0.f ? a : 0.01f * a;
      const float ew = __expf(e);
      const uint4 zz = ((const uint4*)zd)[(size_t)u * 16 + sub];
      ews += ew;
      accf[0] += ew * __uint_as_float(zz.x << 16);
      accf[1] += ew * __uint_as_float(zz.x & 0xffff0000u);
      accf[2] += ew * __uint_as_float(zz.y << 16);
      accf[3] += ew * __uint_as_float(zz.y & 0xffff0000u);
      accf[4] += ew * __uint_as_float(zz.z << 16);
      accf[5] += ew * __uint_as_float(zz.z & 0xffff0000u);
      accf[6] += ew * __uint_as_float(zz.w << 16);
      accf[7] += ew * __uint_as_float(zz.w & 0xffff0000u);
    }

#pragma unroll
    for (int off = 16; off <= 32; off <<= 1) {
      ews += __shfl_xor(ews, off, 64);
#pragma unroll
      for (int j = 0; j < 8; ++j) accf[j] += __shfl_xor(accf[j], off, 64);
    }

    if (grp == 0) {
      const float inv = (end > beg) ? 1.f / ews : 0.f;
      float4 olo = make_float4(accf[0] * inv, accf[2] * inv, accf[4] * inv, accf[6] * inv);
      float4 ohi = make_float4(accf[1] * inv, accf[3] * inv, accf[5] * inv, accf[7] * inv);
      ((float4*)out)[(size_t)v * 32 + sub] = olo;
      ((float4*)out)[(size_t)v * 32 + 16 + sub] = ohi;
    }
  }
}

extern "C" void kernel_launch(void* const* d_in, const int* in_sizes, int n_in,
                              void* d_out, int out_size, void* d_ws, size_t ws_size,
                              hipStream_t stream) {
  const float* h = (const float*)d_in[0];
  const float* emb = (const float*)d_in[1];
  const float* W = (const float*)d_in[2];
  const float* wfc = (const float*)d_in[3];
  const float* wemb = (const float*)d_in[4];
  const int* src = (const int*)d_in[5];
  const int* dst = (const int*)d_in[6];
  const int n = in_sizes[0] / D;
  const int E = in_sizes[5];
  const int NB = (n + BDST - 1) >> BSH;
  const int CHSZ = (E + NCH - 1) / NCH;
  const int M = NB * NCH;
  const int G1 = (M + 1023) / 1024;

  char* ws = (char*)d_ws;
  size_t off = 0;
  auto alloc = [&](size_t bytes) {
    void* p = ws + off;
    off = (off + bytes + 255) & ~(size_t)255;
    return p;
  };
  unsigned* zd = (unsigned*)alloc((size_t)n * 64 * 4);
  unsigned short* Wb = (unsigned short*)alloc(D * D * 2);
  float* a_src = (float*)alloc((size_t)n * 4);
  float* a_dst = (float*)alloc((size_t)n * 4);
  int* cnt = (int*)alloc((size_t)M * 4);
  int* partial = (int*)alloc((size_t)G1 * 4);
  int* chunk_off = (int*)alloc((size_t)G1 * 4);
  unsigned* binrec = (unsigned*)alloc((size_t)E * 4);
  (void)off;
  (void)ws_size;

  k_wconv<<<(D * D / 4 + 255) / 256, 256, 0, stream>>>(W, Wb);
  k_lin<<<(n + 63) / 64, 256, 0, stream>>>(h, Wb, wfc, emb, wemb, zd, a_src, a_dst, n);
  k_chist<<<NCH, 256, 0, stream>>>(dst, cnt, E, NB, CHSZ);
  ks1<<<G1, 256, 0, stream>>>(cnt, partial, M);
  ks2<<<1, 256, 0, stream>>>(partial, chunk_off, G1);
  ks3<<<G1, 256, 0, stream>>>(cnt, chunk_off, M);
  k_cscat<<<NCH, 256, 0, stream>>>(src, dst, cnt, binrec, E, NB, CHSZ);
  k_bagg<<<NB, 256, 0, stream>>>(binrec, cnt, zd, a_src, a_dst, (float*)d_out, n, E, NB);
}

// Round 8
// 138.259 us; speedup vs baseline: 1.2510x; 1.2510x over previous
//
#include <hip/hip_runtime.h>
#include <hip/hip_bf16.h>

#define D 128
#define BSH 7            // 128 dsts per bin
#define BDST 128
#define NCHK 256         // edge chunks for k_hscat
#define CAPB 5120        // padded records per bin (mean 4096, +16 sigma)

typedef __attribute__((ext_vector_type(8))) short short8;
typedef __attribute__((ext_vector_type(4))) float f32x4;

__device__ __forceinline__ unsigned short f2bf(float f) {
  unsigned u = __float_as_uint(f);
  unsigned r = (u + 0x7FFFu + ((u >> 16) & 1u)) >> 16;
  return (unsigned short)r;
}

// ---------------- K0: W fp32 -> bf16 ------------------------------------------
__global__ __launch_bounds__(256) void k_wconv(const float* __restrict__ W,
                                               unsigned short* __restrict__ Wb) {
  const int i = blockIdx.x * 256 + threadIdx.x;
  float4 f = ((const float4*)W)[i];
  ushort4 o;
  o.x = f2bf(f.x); o.y = f2bf(f.y); o.z = f2bf(f.z); o.w = f2bf(f.w);
  ((ushort4*)Wb)[i] = o;
}

// ---------------- K1: z = h@W^T (MFMA) + fused s_fc AND emb dots --------------
__global__ __launch_bounds__(256) void k_lin(const float* __restrict__ h,
                                             const unsigned short* __restrict__ Wb,
                                             const float* __restrict__ w_fc,
                                             const float* __restrict__ emb,
                                             const float* __restrict__ w_emb,
                                             unsigned* __restrict__ zd,
                                             float* __restrict__ a_src,
                                             float* __restrict__ a_dst, int n) {
  __shared__ float sfs[4][16], sfd[4][16];
  const int lane = threadIdx.x & 63;
  const int wid = threadIdx.x >> 6;
  const int m0 = blockIdx.x * 64 + wid * 16;
  if (m0 >= n) return;
  const int c = lane & 15;
  const int g = lane >> 4;

  int arow = m0 + c;
  if (arow >= n) arow = n - 1;
  const float4* hrow = (const float4*)(h + (size_t)arow * 128);

  short8 afr[4];
#pragma unroll
  for (int s = 0; s < 4; ++s) {
    float4 f0 = hrow[8 * s + 2 * g];
    float4 f1 = hrow[8 * s + 2 * g + 1];
    short8 a;
    a[0] = (short)f2bf(f0.x); a[1] = (short)f2bf(f0.y);
    a[2] = (short)f2bf(f0.z); a[3] = (short)f2bf(f0.w);
    a[4] = (short)f2bf(f1.x); a[5] = (short)f2bf(f1.y);
    a[6] = (short)f2bf(f1.z); a[7] = (short)f2bf(f1.w);
    afr[s] = a;
  }

  f32x4 acc[8];
#pragma unroll
  for (int t = 0; t < 8; ++t) acc[t] = (f32x4){0.f, 0.f, 0.f, 0.f};

#pragma unroll
  for (int s = 0; s < 4; ++s) {
#pragma unroll
    for (int t = 0; t < 8; ++t) {
      short8 b = *(const short8*)(Wb + ((size_t)(t * 16 + c) * 128 + 32 * s + 8 * g));
      acc[t] = __builtin_amdgcn_mfma_f32_16x16x32_bf16(afr[s], b, acc[t], 0, 0, 0);
    }
  }

  float wfs[8], wfd[8];
#pragma unroll
  for (int t = 0; t < 8; ++t) {
    wfs[t] = w_fc[t * 16 + c];
    wfd[t] = w_fc[128 + t * 16 + c];
  }

  const int rbase = m0 + 4 * g;
#pragma unroll
  for (int r = 0; r < 4; ++r) {
    const int row = rbase + r;
    if (row < n) {
#pragma unroll
      for (int tp = 0; tp < 4; ++tp) {
        unsigned dw = ((unsigned)f2bf(acc[tp + 4][r]) << 16) | (unsigned)f2bf(acc[tp][r]);
        zd[(size_t)row * 64 + tp * 16 + c] = dw;
      }
    }
    float ps = 0.f, pd = 0.f;
#pragma unroll
    for (int t = 0; t < 8; ++t) {
      ps += acc[t][r] * wfs[t];
      pd += acc[t][r] * wfd[t];
    }
#pragma unroll
    for (int off = 1; off < 16; off <<= 1) {
      ps += __shfl_xor(ps, off, 64);
      pd += __shfl_xor(pd, off, 64);
    }
    if (c == 0) {
      sfs[wid][4 * g + r] = ps;
      sfd[wid][4 * g + r] = pd;
    }
  }
  __syncthreads();

  const int nloc = lane >> 2;
  const int qc = lane & 3;
  const int node2 = m0 + nloc;
  float es = 0.f, ed = 0.f;
  if (node2 < n) {
    const float4* er = (const float4*)(emb + (size_t)node2 * 128 + qc * 32);
    const float4* wsp = (const float4*)(w_emb + qc * 32);
    const float4* wdp = (const float4*)(w_emb + 128 + qc * 32);
#pragma unroll
    for (int j = 0; j < 8; ++j) {
      float4 e4 = er[j], s4 = wsp[j], d4 = wdp[j];
      es += e4.x * s4.x + e4.y * s4.y + e4.z * s4.z + e4.w * s4.w;
      ed += e4.x * d4.x + e4.y * d4.y + e4.z * d4.z + e4.w * d4.w;
    }
  }
  es += __shfl_xor(es, 1, 64); es += __shfl_xor(es, 2, 64);
  ed += __shfl_xor(ed, 1, 64); ed += __shfl_xor(ed, 2, 64);
  if (qc == 0 && node2 < n) {
    a_src[node2] = es + sfs[wid][nloc];
    a_dst[node2] = ed + sfd[wid][nloc];
  }
}

// ---------------- K2: chunk hist + atomic reserve + scatter to padded bins ----
__global__ __launch_bounds__(256) void k_hscat(const int* __restrict__ src,
                                               const int* __restrict__ dst,
                                               int* __restrict__ bincur,
                                               unsigned* __restrict__ binrec,
                                               int E, int NB, int CHSZ) {
  __shared__ int hl[512];
  __shared__ int cur[512];
  const int tid = threadIdx.x, c = blockIdx.x;
  for (int i = tid; i < NB; i += 256) hl[i] = 0;
  __syncthreads();
  const int beg = c * CHSZ, end = min(beg + CHSZ, E);
  for (int i = beg + tid; i < end; i += 256) atomicAdd(&hl[dst[i] >> BSH], 1);
  __syncthreads();
  for (int b = tid; b < NB; b += 256) {
    int cb = hl[b];
    cur[b] = cb > 0 ? atomicAdd(&bincur[b], cb) : 0;
  }
  __syncthreads();
  for (int i = beg + tid; i < end; i += 256) {
    int d = dst[i];
    int b = d >> BSH;
    int pos = atomicAdd(&cur[b], 1);
    binrec[(size_t)b * CAPB + pos] =
        ((unsigned)src[i] << BSH) | (unsigned)(d & (BDST - 1));
  }
}

// ---------------- K3: per-bin local counting sort -> padded csr + row2 --------
__global__ __launch_bounds__(256) void k_build(const unsigned* __restrict__ binrec,
                                               const int* __restrict__ bincur,
                                               int2* __restrict__ row2,
                                               int* __restrict__ csr, int n) {
  __shared__ int hist[BDST], lrow[BDST], cur[BDST];
  const int tid = threadIdx.x, b = blockIdx.x;
  const int cntb = bincur[b];
  const unsigned* rb = binrec + (size_t)b * CAPB;
  const int base = b * CAPB;

  if (tid < BDST) hist[tid] = 0;
  __syncthreads();
  for (int i = tid; i < cntb; i += 256) atomicAdd(&hist[rb[i] & (BDST - 1)], 1);
  __syncthreads();
  if (tid < BDST) lrow[tid] = hist[tid];
  __syncthreads();
  for (int off = 1; off < BDST; off <<= 1) {
    int a = (tid < BDST && tid >= off) ? lrow[tid - off] : 0;
    __syncthreads();
    if (tid < BDST) lrow[tid] += a;
    __syncthreads();
  }
  if (tid < BDST) {
    int e = lrow[tid];
    int s = e - hist[tid];
    cur[tid] = s;
    int v = b * BDST + tid;
    if (v < n) row2[v] = make_int2(base + s, base + e);
  }
  __syncthreads();
  for (int i = tid; i < cntb; i += 256) {
    unsigned r = rb[i];
    int pos = base + atomicAdd(&cur[r & (BDST - 1)], 1);
    csr[pos] = (int)(r >> BSH);
  }
}

// ---------------- K4: single-pass weighted aggregation (paired-dword z) -------
__global__ __launch_bounds__(256) void k_agg(const unsigned* __restrict__ zd,
                                             const float* __restrict__ a_src,
                                             const float* __restrict__ a_dst,
                                             const int2* __restrict__ row2,
                                             const int* __restrict__ csr,
                                             float* __restrict__ out, int n) {
  const int lane = threadIdx.x & 63;
  const int grp = lane >> 4;
  const int sub = lane & 15;
  const int v = blockIdx.x * 4 + (threadIdx.x >> 6);
  if (v >= n) return;
  const int2 be = row2[v];
  const int beg = be.x, end = be.y;
  const float adv = a_dst[v];

  float accf[8];
#pragma unroll
  for (int j = 0; j < 8; ++j) accf[j] = 0.f;
  float ews = 0.f;

#pragma unroll 2
  for (int i = beg + grp; i < end; i += 4) {
    const int u = csr[i];
    const float a = a_src[u] + adv;
    const float e = a > 0.f ? a : 0.01f * a;
    const float ew = __expf(e);
    const uint4 zz = ((const uint4*)zd)[(size_t)u * 16 + sub];
    ews += ew;
    accf[0] += ew * __uint_as_float(zz.x << 16);
    accf[1] += ew * __uint_as_float(zz.x & 0xffff0000u);
    accf[2] += ew * __uint_as_float(zz.y << 16);
    accf[3] += ew * __uint_as_float(zz.y & 0xffff0000u);
    accf[4] += ew * __uint_as_float(zz.z << 16);
    accf[5] += ew * __uint_as_float(zz.z & 0xffff0000u);
    accf[6] += ew * __uint_as_float(zz.w << 16);
    accf[7] += ew * __uint_as_float(zz.w & 0xffff0000u);
  }

#pragma unroll
  for (int off = 16; off <= 32; off <<= 1) {
    ews += __shfl_xor(ews, off, 64);
#pragma unroll
    for (int j = 0; j < 8; ++j) accf[j] += __shfl_xor(accf[j], off, 64);
  }

  if (grp == 0) {
    const float inv = (end > beg) ? 1.f / ews : 0.f;
    float4 olo = make_float4(accf[0] * inv, accf[2] * inv, accf[4] * inv, accf[6] * inv);
    float4 ohi = make_float4(accf[1] * inv, accf[3] * inv, accf[5] * inv, accf[7] * inv);
    ((float4*)out)[(size_t)v * 32 + sub] = olo;
    ((float4*)out)[(size_t)v * 32 + 16 + sub] = ohi;
  }
}

extern "C" void kernel_launch(void* const* d_in, const int* in_sizes, int n_in,
                              void* d_out, int out_size, void* d_ws, size_t ws_size,
                              hipStream_t stream) {
  const float* h = (const float*)d_in[0];
  const float* emb = (const float*)d_in[1];
  const float* W = (const float*)d_in[2];
  const float* wfc = (const float*)d_in[3];
  const float* wemb = (const float*)d_in[4];
  const int* src = (const int*)d_in[5];
  const int* dst = (const int*)d_in[6];
  const int n = in_sizes[0] / D;
  const int E = in_sizes[5];
  const int NB = (n + BDST - 1) >> BSH;
  const int CHSZ = (E + NCHK - 1) / NCHK;

  char* ws = (char*)d_ws;
  size_t off = 0;
  auto alloc = [&](size_t bytes) {
    void* p = ws + off;
    off = (off + bytes + 255) & ~(size_t)255;
    return p;
  };
  unsigned* zd = (unsigned*)alloc((size_t)n * 64 * 4);          // 12.8 MB
  unsigned short* Wb = (unsigned short*)alloc(D * D * 2);
  float* a_src = (float*)alloc((size_t)n * 4);
  float* a_dst = (float*)alloc((size_t)n * 4);
  int* bincur = (int*)alloc((size_t)NB * 4);
  int2* row2 = (int2*)alloc((size_t)n * 8);
  unsigned* binrec = (unsigned*)alloc((size_t)NB * CAPB * 4);   // 8.0 MB
  int* csr = (int*)alloc((size_t)NB * CAPB * 4);                // 8.0 MB
  (void)off;
  (void)ws_size;

  (void)hipMemsetAsync(bincur, 0, (size_t)NB * 4, stream);
  k_wconv<<<(D * D / 4 + 255) / 256, 256, 0, stream>>>(W, Wb);
  k_lin<<<(n + 63) / 64, 256, 0, stream>>>(h, Wb, wfc, emb, wemb, zd, a_src, a_dst, n);
  k_hscat<<<NCHK, 256, 0, stream>>>(src, dst, bincur, binrec, E, NB, CHSZ);
  k_build<<<NB, 256, 0, stream>>>(binrec, bincur, row2, csr, n);
  k_agg<<<(n + 3) / 4, 256, 0, stream>>>(zd, a_src, a_dst, row2, csr, (float*)d_out, n);
}